// Round 7
// baseline (65.497 us; speedup 1.0000x reference)
//
#include <hip/hip_runtime.h>
#include <math.h>

#define N 16384
#define LIMIT 8192
#define NT 1024
#define G 16
#define EPT 16

// key = (float_bits(score) << 14) | index  -- 44-bit unique sort key.
// score = sigmoid(y) in (0,1] => positive float, bits <= 0x3F800000 < 2^30,
// monotone; index < 2^14. (score,index) lex order == jnp stable argsort.
// T = rank-(LIMIT-1) key; keep element i iff key_i <= T.
//
// ONE kernel, 16 blocks x 1024 threads. Every block redundantly computes all
// N scores (16/thread, in registers), the pass-0 histogram, and the radix
// selection -- zero inter-block communication, no d_ws, no grid sync (r4/r5
// showed coop launch +35us, manual fence barrier +18us). Block b writes only
// slice [1024b, 1024b+1024) of both outputs (threads tid>>6 == b).
// Selection: pass0 10 bits (LDS hist, 4-way spread) -> pass1 12 bits -> the
// surviving 22-bit bin has M elements (E[M]~1); if M<=64, gather residuals
// and rank-select within one wave (replaces two more hist passes + scans);
// exact 11+11-bit fallback otherwise.

__device__ __forceinline__ unsigned long long make_key(float s, int i) {
    return ((unsigned long long)__float_as_uint(s) << 14) | (unsigned int)i;
}

// Scan/select over tot[0..256*W): rank r straddle bin. Also exports the
// chosen bin's count (M) to *m_sh. Requires barrier-before (tot complete).
template <int W, int WIDTH>
__device__ __forceinline__ void scan_select(unsigned int* tot,
                                            unsigned int* partial,
                                            unsigned long long* prefix_sh,
                                            unsigned int* r_sh,
                                            unsigned int* m_sh) {
    const int tid = threadIdx.x;
    const unsigned int r = *r_sh;          // valid: written before prior barrier
    if (tid < 256) {
        unsigned int p = 0;
#pragma unroll
        for (int q = 0; q < W / 4; ++q) {
            uint4 v = ((const uint4*)tot)[tid * (W / 4) + q];
            p += v.x + v.y + v.z + v.w;
        }
        partial[tid] = p;
    }
    __syncthreads();
    if (tid < 64) {                        // wave 0: wave-synchronous
        unsigned int p0 = partial[4*tid+0], p1 = partial[4*tid+1],
                     p2 = partial[4*tid+2], p3 = partial[4*tid+3];
        const unsigned int g4 = p0 + p1 + p2 + p3;
        unsigned int incl = g4;
#pragma unroll
        for (int d = 1; d < 64; d <<= 1) {
            unsigned int up = __shfl_up(incl, d, 64);
            if (tid >= d) incl += up;
        }
        unsigned long long ball = __ballot(incl > r);   // nonzero by rank invariant
        int L = __ffsll((long long)ball) - 1;
        if (tid == L) {
            unsigned int cum = incl - g4;
            unsigned int pp[4] = {p0, p1, p2, p3};
            int grp = -1;
#pragma unroll
            for (int k = 0; k < 4; ++k)
                if (grp < 0) { if (cum + pp[k] > r) grp = 4*L + k; else cum += pp[k]; }
            unsigned int c[W];
#pragma unroll
            for (int q = 0; q < W / 4; ++q) {
                uint4 v = ((const uint4*)tot)[grp * (W / 4) + q];
                c[4*q+0] = v.x; c[4*q+1] = v.y; c[4*q+2] = v.z; c[4*q+3] = v.w;
            }
            int b = -1; unsigned int mm = 0;
#pragma unroll
            for (int k = 0; k < W; ++k)
                if (b < 0) {
                    if (cum + c[k] > r) { b = grp * W + k; mm = c[k]; }
                    else cum += c[k];
                }
            *r_sh = r - cum;
            *m_sh = mm;
            *prefix_sh = (*prefix_sh << WIDTH) | (unsigned long long)b;
        }
    }
    __syncthreads();
}

__global__ __launch_bounds__(NT)
void mono_kernel(const float* __restrict__ x, const float* __restrict__ w,
                 float* __restrict__ out) {
    __shared__ __attribute__((aligned(16))) unsigned int hist0[4096]; // 1024 bins x4 spread
    __shared__ __attribute__((aligned(16))) unsigned int tot[1024];
    __shared__ __attribute__((aligned(16))) unsigned int hist1[4096];
    __shared__ __attribute__((aligned(16))) unsigned int partial[256];
    __shared__ unsigned long long prefix_sh;
    __shared__ unsigned int r_sh, m_sh, ccnt, tlow_sh;
    __shared__ unsigned int cand[64];

    const int tid = threadIdx.x;
    const int blk = blockIdx.x;
    const int base = tid * EPT;            // global chunk -- block-independent

    float wv[7];
#pragma unroll
    for (int t = 0; t < 7; ++t) wv[t] = w[t];

    // x window [base-3, base+EPT+3) straight from global (L2-hot, 64KB)
    float win[EPT + 6];
    const float4* xv = (const float4*)(x + base);
#pragma unroll
    for (int q = 0; q < 4; ++q) {
        float4 v = xv[q];
        win[3 + 4*q + 0] = v.x; win[3 + 4*q + 1] = v.y;
        win[3 + 4*q + 2] = v.z; win[3 + 4*q + 3] = v.w;
    }
#pragma unroll
    for (int t = 0; t < 3; ++t) {
        int jl = base - 3 + t;
        win[t] = (jl >= 0) ? x[jl] : 0.f;
        int jr = base + EPT + t;
        win[EPT + 3 + t] = (jr < N) ? x[jr] : 0.f;
    }

    // zero LDS while loads are in flight
    hist0[tid] = 0; hist0[tid+1024] = 0; hist0[tid+2048] = 0; hist0[tid+3072] = 0;
    hist1[tid] = 0; hist1[tid+1024] = 0; hist1[tid+2048] = 0; hist1[tid+3072] = 0;
    tot[tid] = 0;
    if (tid == 0) { prefix_sh = 0ULL; r_sh = LIMIT - 1; ccnt = 0; }

    // conv + sigmoid: bit-exact vs numpy (sequential non-contracted mul/add, expf)
    float s[EPT];
#pragma unroll
    for (int k = 0; k < EPT; ++k) {
        float acc = 0.f;
#pragma unroll
        for (int t = 0; t < 7; ++t)
            acc = __fadd_rn(acc, __fmul_rn(win[k + t], wv[t]));
        s[k] = 1.f / (1.f + expf(-acc));
    }

    // block b writes score slice [1024b, 1024b+1024)
    if ((tid >> 6) == blk) {
        float4* so = (float4*)(out + N + base);
#pragma unroll
        for (int q = 0; q < 4; ++q)
            so[q] = make_float4(s[4*q], s[4*q+1], s[4*q+2], s[4*q+3]);
    }
    __syncthreads();                       // zeros + r_sh/prefix/ccnt visible

    // pass 0: histogram key bits [43:34] (= float bits >> 20), 4-way spread
    const int slot = tid & 3;
#pragma unroll
    for (int k = 0; k < EPT; ++k) {
        unsigned int bin = __float_as_uint(s[k]) >> 20;   // < 1024
        atomicAdd(&hist0[(bin << 2) | slot], 1u);
    }
    __syncthreads();
    {
        uint4 v = ((const uint4*)hist0)[tid];
        tot[tid] = v.x + v.y + v.z + v.w;
    }
    __syncthreads();
    scan_select<4, 10>(tot, partial, &prefix_sh, &r_sh, &m_sh);   // prefix = b0

    // pass 1: 12 bits [33:22] among bucket-b0 candidates
    {
        const unsigned long long pref = prefix_sh;
#pragma unroll
        for (int k = 0; k < EPT; ++k) {
            unsigned long long key = make_key(s[k], base + k);
            if ((key >> 34) == pref)
                atomicAdd(&hist1[(unsigned int)(key >> 22) & 4095u], 1u);
        }
    }
    __syncthreads();
    scan_select<16, 12>(hist1, partial, &prefix_sh, &r_sh, &m_sh); // prefix = 22 bits

    unsigned long long T;
    const unsigned int M = m_sh;           // block-uniform
    const unsigned int r1 = r_sh;
    if (M <= 64u) {
        // gather the M low-22-bit residuals, rank-select inside wave 0
        const unsigned long long pref = prefix_sh;
#pragma unroll
        for (int k = 0; k < EPT; ++k) {
            unsigned long long key = make_key(s[k], base + k);
            if ((key >> 22) == pref) {
                unsigned int pos = atomicAdd(&ccnt, 1u);
                cand[pos] = (unsigned int)(key & 0x3FFFFFu);
            }
        }
        __syncthreads();
        if (tid < 64) {
            unsigned int v = (tid < (int)M) ? cand[tid] : 0xFFFFFFFFu;
            unsigned int cnt = 0;
#pragma unroll
            for (int i = 0; i < 64; ++i) {
                unsigned int vi = __shfl(v, i, 64);
                cnt += (vi < v) ? 1u : 0u;   // residuals unique (index bits)
            }
            if (tid < (int)M && cnt == r1) tlow_sh = v;
        }
        __syncthreads();
        T = (prefix_sh << 22) | (unsigned long long)tlow_sh;
    } else {
        // exact fallback: two more passes, 11 bits each (reuse hist1[0..2048))
        hist1[tid] = 0; hist1[tid + 1024] = 0;
        __syncthreads();
        {
            const unsigned long long pref = prefix_sh;
#pragma unroll
            for (int k = 0; k < EPT; ++k) {
                unsigned long long key = make_key(s[k], base + k);
                if ((key >> 22) == pref)
                    atomicAdd(&hist1[(unsigned int)(key >> 11) & 2047u], 1u);
            }
        }
        __syncthreads();
        scan_select<8, 11>(hist1, partial, &prefix_sh, &r_sh, &m_sh);
        hist1[tid] = 0; hist1[tid + 1024] = 0;
        __syncthreads();
        {
            const unsigned long long pref = prefix_sh;
#pragma unroll
            for (int k = 0; k < EPT; ++k) {
                unsigned long long key = make_key(s[k], base + k);
                if ((key >> 11) == pref)
                    atomicAdd(&hist1[(unsigned int)key & 2047u], 1u);
            }
        }
        __syncthreads();
        scan_select<8, 11>(hist1, partial, &prefix_sh, &r_sh, &m_sh);
        T = prefix_sh;
    }

    // block b writes new_x slice [1024b, 1024b+1024)
    if ((tid >> 6) == blk) {
        float4* no = (float4*)(out + base);
#pragma unroll
        for (int q = 0; q < 4; ++q) {
            float4 v; float* vp = &v.x;
#pragma unroll
            for (int e = 0; e < 4; ++e) {
                int k = 4*q + e;
                unsigned long long key = make_key(s[k], base + k);
                vp[e] = (key <= T) ? __fmul_rn(win[3 + k], __fadd_rn(s[k], 1.0f)) : 0.f;
            }
            no[q] = v;
        }
    }
}

extern "C" void kernel_launch(void* const* d_in, const int* in_sizes, int n_in,
                              void* d_out, int out_size, void* d_ws, size_t ws_size,
                              hipStream_t stream) {
    const float* x = (const float*)d_in[0];
    const float* w = (const float*)d_in[1];
    float* out = (float*)d_out;   // [0:N) new_x, [N:2N) attention_score
    mono_kernel<<<G, NT, 0, stream>>>(x, w, out);
}

// Round 8
// 65.483 us; speedup vs baseline: 1.0002x; 1.0002x over previous
//
#include <hip/hip_runtime.h>
#include <math.h>

#define N 16384
#define LIMIT 8192
#define NT 1024
#define G 16
#define EPT 16
#define LO 0x3E800000u   // float bits of 0.25f (2^11-aligned)
#define HI 0x3F800000u   // float bits of 1.0f
#define BSH 11           // bin = (u - LO) >> BSH, 8192 bins
#define NB 8192

// key = (float_bits(score) << 14) | index  -- 44-bit unique sort key.
// score = sigmoid(y) in (0,1) => positive float, monotone bits; index < 2^14.
// (score,index) lex order == jnp stable argsort. T = rank-(LIMIT-1) key;
// keep i iff key_i <= T.
//
// ONE kernel, 16 blocks x 1024 threads, zero inter-block communication
// (r4 coop-launch +35us, r5 fence-barrier +18us, r6/r7 showed splits tie).
// Every block redundantly computes all N scores; block b writes only slice
// [1024b,1024b+1024) of both outputs.
// Selection (fast path): ONE 8192-bin histogram over the value window
// [0.25,1.0) (bin width 2^11 ulps; below-window elements only counted),
// one scan -> straddle bin (expected M~12 elements), wave rank-select of
// 25-bit residuals. Exact fallback (threshold outside window or M>64):
// 4x11-bit full-key radix select (proven r2 structure) -- never taken for
// this input, exact if taken.

__device__ __forceinline__ unsigned long long make_key(float s, int i) {
    return ((unsigned long long)__float_as_uint(s) << 14) | (unsigned int)i;
}

// Straddle-bin search over tot[0..256*W) for rank r. Writes b_sh (bin),
// r_out (residual rank), m_sh (bin count; 0xFFFFFFFF if r >= total).
template <int W>
__device__ __forceinline__ void scan_select(const unsigned int* tot,
                                            unsigned int* partial,
                                            unsigned int r,
                                            unsigned int* b_sh,
                                            unsigned int* r_out,
                                            unsigned int* m_sh) {
    const int tid = threadIdx.x;
    if (tid < 256) {
        unsigned int p = 0;
#pragma unroll
        for (int q = 0; q < W / 4; ++q) {
            uint4 v = ((const uint4*)tot)[tid * (W / 4) + q];
            p += v.x + v.y + v.z + v.w;
        }
        partial[tid] = p;
    }
    __syncthreads();
    if (tid < 64) {                        // wave 0: wave-synchronous
        unsigned int p0 = partial[4*tid+0], p1 = partial[4*tid+1],
                     p2 = partial[4*tid+2], p3 = partial[4*tid+3];
        const unsigned int g4 = p0 + p1 + p2 + p3;
        unsigned int incl = g4;
#pragma unroll
        for (int d = 1; d < 64; d <<= 1) {
            unsigned int up = __shfl_up(incl, d, 64);
            if (tid >= d) incl += up;
        }
        unsigned long long ball = __ballot(incl > r);
        if (ball == 0ULL) {
            if (tid == 0) *m_sh = 0xFFFFFFFFu;      // rank beyond histogram
        } else {
            int L = __ffsll((long long)ball) - 1;
            if (tid == L) {
                unsigned int cum = incl - g4;
                unsigned int pp[4] = {p0, p1, p2, p3};
                int grp = -1;
#pragma unroll
                for (int k = 0; k < 4; ++k)
                    if (grp < 0) { if (cum + pp[k] > r) grp = 4*L + k; else cum += pp[k]; }
                unsigned int c[W];
#pragma unroll
                for (int q = 0; q < W / 4; ++q) {   // batched, constant-indexed
                    uint4 v = ((const uint4*)tot)[grp * (W / 4) + q];
                    c[4*q+0] = v.x; c[4*q+1] = v.y; c[4*q+2] = v.z; c[4*q+3] = v.w;
                }
                int b = -1; unsigned int mm = 0;
#pragma unroll
                for (int k = 0; k < W; ++k)
                    if (b < 0) {
                        if (cum + c[k] > r) { b = grp * W + k; mm = c[k]; }
                        else cum += c[k];
                    }
                *r_out = r - cum;
                *m_sh = mm;
                *b_sh = (unsigned int)b;
            }
        }
    }
    __syncthreads();
}

__global__ __launch_bounds__(NT)
void mono_kernel(const float* __restrict__ x, const float* __restrict__ w,
                 float* __restrict__ out) {
    __shared__ __attribute__((aligned(16))) unsigned int hist[NB];   // 32KB
    __shared__ __attribute__((aligned(16))) unsigned int partial[256];
    __shared__ unsigned int cand[64];
    __shared__ unsigned int b_sh, r1_sh, m_sh, below_sh, ccnt, tlow_sh;

    const int tid = threadIdx.x;
    const int blk = blockIdx.x;
    const int base = tid * EPT;            // global chunk -- block-independent

    float wv[7];
#pragma unroll
    for (int t = 0; t < 7; ++t) wv[t] = w[t];

    // x window [base-3, base+EPT+3) from global (64KB, L2-hot)
    float win[EPT + 6];
    const float4* xv = (const float4*)(x + base);
#pragma unroll
    for (int q = 0; q < 4; ++q) {
        float4 v = xv[q];
        win[3 + 4*q + 0] = v.x; win[3 + 4*q + 1] = v.y;
        win[3 + 4*q + 2] = v.z; win[3 + 4*q + 3] = v.w;
    }
#pragma unroll
    for (int t = 0; t < 3; ++t) {
        int jl = base - 3 + t;
        win[t] = (jl >= 0) ? x[jl] : 0.f;
        int jr = base + EPT + t;
        win[EPT + 3 + t] = (jr < N) ? x[jr] : 0.f;
    }

    // zero LDS while loads are in flight (8 words/thread = 8192)
    ((uint4*)hist)[tid] = make_uint4(0,0,0,0);
    ((uint4*)hist)[tid + 1024] = make_uint4(0,0,0,0);
    if (tid == 0) { below_sh = 0; ccnt = 0; }

    // conv + sigmoid: bit-exact vs numpy (sequential non-contracted mul/add, expf)
    float s[EPT];
#pragma unroll
    for (int k = 0; k < EPT; ++k) {
        float acc = 0.f;
#pragma unroll
        for (int t = 0; t < 7; ++t)
            acc = __fadd_rn(acc, __fmul_rn(win[k + t], wv[t]));
        s[k] = 1.f / (1.f + expf(-acc));
    }

    // block b writes score slice [1024b, 1024b+1024)
    if ((tid >> 6) == blk) {
        float4* so = (float4*)(out + N + base);
#pragma unroll
        for (int q = 0; q < 4; ++q)
            so[q] = make_float4(s[4*q], s[4*q+1], s[4*q+2], s[4*q+3]);
    }
    __syncthreads();                       // zeros + scalars visible

    // window histogram + below-window count
    unsigned int cnt = 0;
#pragma unroll
    for (int k = 0; k < EPT; ++k) {
        const unsigned int u = __float_as_uint(s[k]);
        if (u < LO) ++cnt;
        else if (u < HI) atomicAdd(&hist[(u - LO) >> BSH], 1u);
    }
#pragma unroll
    for (int d = 32; d > 0; d >>= 1) cnt += __shfl_down(cnt, d, 64);
    if ((tid & 63) == 0 && cnt) atomicAdd(&below_sh, cnt);
    __syncthreads();

    const unsigned int r0 = (LIMIT - 1) - below_sh;  // underflow => fallback
    scan_select<32>(hist, partial, r0, &b_sh, &r1_sh, &m_sh);
    const unsigned int M = m_sh;           // block-uniform

    unsigned long long T;
    if (M <= 64u) {
        // gather the M residuals R = (u_low11 << 14) | index (25b, unique),
        // rank-select r1 within wave 0
        const unsigned int b = b_sh, r1 = r1_sh;
#pragma unroll
        for (int k = 0; k < EPT; ++k) {
            const unsigned int u = __float_as_uint(s[k]);
            if (u >= LO && u < HI && ((u - LO) >> BSH) == b) {
                unsigned int pos = atomicAdd(&ccnt, 1u);
                cand[pos] = ((u & 0x7FFu) << 14) | (unsigned int)(base + k);
            }
        }
        __syncthreads();
        if (tid < 64) {
            unsigned int v = (tid < (int)M) ? cand[tid] : 0xFFFFFFFFu;
            unsigned int c = 0;
#pragma unroll
            for (int i = 0; i < 64; ++i) {
                unsigned int vi = __shfl(v, i, 64);
                c += (vi < v) ? 1u : 0u;
            }
            if (tid < (int)M && c == r1) tlow_sh = v;
        }
        __syncthreads();
        const unsigned int R = tlow_sh;
        const unsigned int ustar = LO + (b << BSH) + (R >> 14);
        T = ((unsigned long long)ustar << 14) | (unsigned long long)(R & 0x3FFFu);
    } else {
        // exact generic fallback: 4 x 11-bit MSB radix over full 44-bit keys
        unsigned long long prefix = 0ULL;
        unsigned int r2 = LIMIT - 1;
        for (int p = 0; p < 4; ++p) {
            const int shift = 33 - 11 * p;
            hist[tid] = 0; hist[tid + 1024] = 0;
            __syncthreads();
#pragma unroll
            for (int k = 0; k < EPT; ++k) {
                unsigned long long key = make_key(s[k], base + k);
                if ((key >> (shift + 11)) == prefix)
                    atomicAdd(&hist[(unsigned int)(key >> shift) & 2047u], 1u);
            }
            __syncthreads();
            scan_select<8>(hist, partial, r2, &b_sh, &r1_sh, &m_sh);
            prefix = (prefix << 11) | (unsigned long long)b_sh;
            r2 = r1_sh;
        }
        T = prefix;
    }

    // block b writes new_x slice [1024b, 1024b+1024)
    if ((tid >> 6) == blk) {
        float4* no = (float4*)(out + base);
#pragma unroll
        for (int q = 0; q < 4; ++q) {
            float4 v; float* vp = &v.x;
#pragma unroll
            for (int e = 0; e < 4; ++e) {
                int k = 4*q + e;
                unsigned long long key = make_key(s[k], base + k);
                vp[e] = (key <= T) ? __fmul_rn(win[3 + k], __fadd_rn(s[k], 1.0f)) : 0.f;
            }
            no[q] = v;
        }
    }
}

extern "C" void kernel_launch(void* const* d_in, const int* in_sizes, int n_in,
                              void* d_out, int out_size, void* d_ws, size_t ws_size,
                              hipStream_t stream) {
    const float* x = (const float*)d_in[0];
    const float* w = (const float*)d_in[1];
    float* out = (float*)d_out;   // [0:N) new_x, [N:2N) attention_score
    mono_kernel<<<G, NT, 0, stream>>>(x, w, out);
}